// Round 14
// baseline (182.288 us; speedup 1.0000x reference)
//
#include <hip/hip_runtime.h>
#include <stdint.h>

typedef short bf8v __attribute__((ext_vector_type(8)));
typedef float f4v  __attribute__((ext_vector_type(4)));
typedef short s8v  __attribute__((ext_vector_type(8)));
typedef short s4v  __attribute__((ext_vector_type(4)));
typedef int   i2v  __attribute__((ext_vector_type(2)));

__device__ __forceinline__ float bf2f(short b){
  unsigned u = ((unsigned)(unsigned short)b) << 16;
  union { unsigned u; float f; } c; c.u = u; return c.f;
}
__device__ __forceinline__ short f2bf(float f){
  union { float f; unsigned u; } c; c.f = f;
  unsigned r = (c.u + 0x7FFFu + ((c.u >> 16) & 1u)) >> 16;
  return (short)r;
}
__device__ __forceinline__ void gload16(const short* g, short* l){
  __builtin_amdgcn_global_load_lds(
      (const __attribute__((address_space(1))) void*)g,
      (__attribute__((address_space(3))) void*)l, 16, 0, 0);
}
// bijective XCD regroup (m204)
__device__ __forceinline__ int xcd_remap(int wg, int nwg){
  int q = nwg >> 3, r = nwg & 7;
  int xcd = wg & 7, idx = wg >> 3;
  return (xcd < r ? xcd*(q+1) : r*(q+1) + (xcd - r)*q) + idx;
}

// ---------------- setup: prep (block 0) + cvt2bf + weight transpose ----------
__global__ __launch_bounds__(256) void setup_kernel(
    const int* lx, const int* lm, int* meta,
    const float* __restrict__ x, const float* __restrict__ mem,
    short* __restrict__ xb, short* __restrict__ mb, long long n, int nblk_cvt,
    const float* __restrict__ Wq, const float* __restrict__ Wk,
    const float* __restrict__ Wv, const float* __restrict__ Wo,
    const float* __restrict__ W1, const float* __restrict__ W2,
    short* __restrict__ WqT, short* __restrict__ WkT,
    short* __restrict__ WvT, short* __restrict__ WoT,
    short* __restrict__ W1T, short* __restrict__ W2T){
  __shared__ int sjp[9], skvc[8];
  __shared__ float tile[32][33];
  int tid = threadIdx.x;
  int bid = blockIdx.x;

  if (bid == 0){
    if (tid == 0){
      int is64 = ((lx[1] | lx[3] | lx[5] | lx[7]) == 0) ? 1 : 0;
      int ox = 0, om = 0;
      for (int b = 0; b < 8; ++b){
        int a = is64 ? lx[2*b] : lx[b];
        int c = is64 ? lm[2*b] : lm[b];
        meta[b] = a; meta[8+b] = c;
        meta[16+b] = ox; meta[25+b] = om;
        ox += a; om += c;
      }
      meta[24] = ox; meta[33] = om;
      int jp = 0;
      for (int b = 0; b < 8; ++b){
        int Lm_ = meta[8+b];
        // chunk target 128, up to 8 chunks -> uniform <=4-iter jobs
        int kvc = (Lm_ + 127) / 128; if (kvc > 8) kvc = 8; if (kvc < 1) kvc = 1;
        int clen = (((Lm_ + kvc - 1) / kvc) + 31) & ~31;
        meta[34+b] = kvc; meta[42+b] = clen;
        meta[50+b] = jp;
        sjp[b] = jp; skvc[b] = kvc;
        int qt = (meta[b] + 63) / 64;
        jp += qt * kvc * 8;
      }
      meta[58] = jp;
      sjp[8] = jp;
    }
    __syncthreads();
    int njobs = sjp[8];
    for (int j = tid; j < njobs; j += blockDim.x){
      int b = 0;
      #pragma unroll
      for (int i = 1; i < 8; ++i) if (j >= sjp[i]) b = i;
      int local = j - sjp[b];
      int kvc = skvc[b];
      int h = local & 7;
      int r = local >> 3;
      int c = r % kvc;
      int qt = r / kvc;
      meta[64+j] = b | (h << 4) | (c << 7) | (qt << 11);
    }
    return;
  }

  if (bid <= nblk_cvt){
    long long t = (long long)(bid - 1) * 256 + tid;
    long long i = t * 8;
    const float* s; short* d;
    if (i < n){ s = x + i; d = xb + i; }
    else {
      i -= n; if (i >= n) return;
      s = mem + i; d = mb + i;
    }
    float4 f0 = *(const float4*)s;
    float4 f1 = *(const float4*)(s + 4);
    s8v o;
    o[0]=f2bf(f0.x); o[1]=f2bf(f0.y); o[2]=f2bf(f0.z); o[3]=f2bf(f0.w);
    o[4]=f2bf(f1.x); o[5]=f2bf(f1.y); o[6]=f2bf(f1.z); o[7]=f2bf(f1.w);
    *(s8v*)d = o;
    return;
  }

  int wbid = bid - 1 - nblk_cvt;       // 0 .. 3071
  const float* W; short* WT; int K, N, t0;
  if      (wbid <  256){ W=Wq; WT=WqT; K=512;  N=512;  t0=0;    }
  else if (wbid <  512){ W=Wk; WT=WkT; K=512;  N=512;  t0=256;  }
  else if (wbid <  768){ W=Wv; WT=WvT; K=512;  N=512;  t0=512;  }
  else if (wbid < 1024){ W=Wo; WT=WoT; K=512;  N=512;  t0=768;  }
  else if (wbid < 2048){ W=W1; WT=W1T; K=512;  N=2048; t0=1024; }
  else                 { W=W2; WT=W2T; K=2048; N=512;  t0=2048; }
  int lt = wbid - t0;
  int ntn = N / 32;
  int tk = lt / ntn, tn = lt % ntn;
  int r0 = tid >> 5, c = tid & 31;
  #pragma unroll
  for (int i = 0; i < 4; ++i){
    int r = r0 + i*8;
    tile[r][c] = W[(long)(tk*32 + r)*N + tn*32 + c];
  }
  __syncthreads();
  #pragma unroll
  for (int i = 0; i < 4; ++i){
    int r = r0 + i*8;
    WT[(long)(tn*32 + r)*K + tk*32 + c] = f2bf(tile[c][r]);
  }
}

// ---------------- bf16 MFMA GEMM core (BM=64 x BN=128, BK=32), K-chunked -----
__device__ __forceinline__ void stage_g64(const short* A, const short* Bt,
    long brow, long bcol, int M, int N, int K, int t,
    short* Als, short* Bls){
  int tid = threadIdx.x;
  {
    int cc = tid;
    int row = cc >> 2, slot = cc & 3;
    int cg = slot ^ ((row >> 1) & 3);
    long ar = brow + row; if (ar >= M) ar = M - 1;
    gload16(A + ar*(long)K + t + cg*8, &Als[cc*8]);
  }
  #pragma unroll
  for (int i = 0; i < 2; ++i){
    int cc = i*256 + tid;
    int row = cc >> 2, slot = cc & 3;
    int cg = slot ^ ((row >> 1) & 3);
    long br = bcol + row; if (br >= N) br = N - 1;
    gload16(Bt + br*(long)K + t + cg*8, &Bls[cc*8]);
  }
}

__device__ __forceinline__ void gemm_core64(const short* A, const short* Bt,
    short* __restrict__ Cb, const float* __restrict__ bias,
    int M, int N, int K, int k0, int klen,
    float scale, int relu, int colmajor,
    long brow, long bcol, short* Als, short* Bls){
  int tid = threadIdx.x;
  int lane = tid & 63, w = tid >> 6;
  int wcol = w * 32;
  int l15 = lane & 15, l4 = lane >> 4;

  f4v acc[4][2];
  #pragma unroll
  for (int m = 0; m < 4; ++m)
    #pragma unroll
    for (int n = 0; n < 2; ++n) acc[m][n] = (f4v){0.f,0.f,0.f,0.f};

  int nt = klen / 32;
  stage_g64(A, Bt, brow, bcol, M, N, K, k0, Als, Bls);
  for (int t = 0; t < nt; ++t){
    __syncthreads();            // stage(t) landed; buf[(t+1)&1] free
    if (t + 1 < nt)
      stage_g64(A, Bt, brow, bcol, M, N, K, k0 + (t+1)*32,
                Als + ((t+1)&1)*2048, Bls + ((t+1)&1)*4096);
    const short* Ab = Als + (t&1)*2048;
    const short* Bb = Bls + (t&1)*4096;
    bf8v a[4], b[2];
    #pragma unroll
    for (int m = 0; m < 4; ++m){
      int row = m*16 + l15;
      a[m] = *(const bf8v*)&Ab[row*32 + (l4 ^ ((row >> 1) & 3))*8];
    }
    #pragma unroll
    for (int n = 0; n < 2; ++n){
      int row = wcol + n*16 + l15;
      b[n] = *(const bf8v*)&Bb[row*32 + (l4 ^ ((row >> 1) & 3))*8];
    }
    #pragma unroll
    for (int m = 0; m < 4; ++m){
      acc[m][0] = __builtin_amdgcn_mfma_f32_16x16x32_bf16(a[m], b[0], acc[m][0], 0, 0, 0);
      acc[m][1] = __builtin_amdgcn_mfma_f32_16x16x32_bf16(a[m], b[1], acc[m][1], 0, 0, 0);
    }
  }

  #pragma unroll
  for (int m = 0; m < 4; ++m){
    #pragma unroll
    for (int n = 0; n < 2; ++n){
      long col = bcol + wcol + n*16 + l15;
      float bi = (bias != nullptr && col < N) ? bias[col] : 0.f;
      #pragma unroll
      for (int j = 0; j < 4; ++j){
        long row = brow + m*16 + 4*l4 + j;
        if (row < M && col < N){
          float v = acc[m][n][j] * scale + bi;
          if (relu) v = fmaxf(v, 0.f);
          Cb[colmajor ? (col*(long)M + row) : (row*(long)N + col)] = f2bf(v);
        }
      }
    }
  }
}

// generic launcher: grid = (ncol, nrow, nchunk), XCD-swizzled; chunk c -> C+c*M*N
__global__ __launch_bounds__(256) void gemm64(
    const short* __restrict__ A, const short* __restrict__ Bt,
    short* __restrict__ C, const float* __restrict__ bias,
    int M, int N, int K, int klen, float scale, int relu, int colmajor){
  __shared__ __align__(16) short Als[2*64*32];
  __shared__ __align__(16) short Bls[2*128*32];
  int ncol = gridDim.x, nrow = gridDim.y;
  int nwg = ncol * nrow * gridDim.z;
  int wg = blockIdx.x + ncol*(blockIdx.y + nrow*blockIdx.z);
  int lg = xcd_remap(wg, nwg);
  int xx = lg % ncol;
  int yy = (lg / ncol) % nrow;
  int chunk = lg / (ncol * nrow);
  gemm_core64(A, Bt, C + (long)chunk * M * N, bias, M, N, K, chunk*klen, klen,
              scale, relu, colmajor,
              (long)yy * 64, (long)xx * 128, Als, Bls);
}

// fused QKV (XCD-swizzled): 12 x-tiles (4 col-tiles x {Q,K,V}).
__global__ __launch_bounds__(256) void gemm_qkv(
    const short* __restrict__ xb, const short* __restrict__ mb,
    const short* __restrict__ WqT, const short* __restrict__ WkT,
    const short* __restrict__ WvT,
    short* __restrict__ Qb, short* __restrict__ Kbf, short* __restrict__ Vtb,
    int total){
  __shared__ __align__(16) short Als[2*64*32];
  __shared__ __align__(16) short Bls[2*128*32];
  int nwg = 12 * gridDim.y;
  int wg = blockIdx.x + 12*blockIdx.y;
  int lg = xcd_remap(wg, nwg);
  int xx = lg % 12;
  int yy = lg / 12;
  int seg = xx >> 2;
  const short* A  = (seg == 0) ? xb : mb;
  const short* Bt = (seg == 0) ? WqT : ((seg == 1) ? WkT : WvT);
  short* C        = (seg == 0) ? Qb  : ((seg == 1) ? Kbf : Vtb);
  float scale     = (seg == 0) ? 0.125f : 1.f;
  int colmajor    = (seg == 2);
  gemm_core64(A, Bt, C, nullptr, total, 512, 512, 0, 512, scale, 0, colmajor,
              (long)yy * 64, (long)(xx & 3) * 128, Als, Bls);
}

// ---------------- flash attention: split-kv jobs, swapped QK^T ---------------
// partial slot stride is 8 (kvc <= 8)
__global__ __launch_bounds__(256) void attn_kernel(
    const short* __restrict__ Q, const short* __restrict__ Kb,
    const short* __restrict__ Vt, short* __restrict__ Ob,
    short* __restrict__ Opart, float* __restrict__ mlpart,
    const int* __restrict__ meta, int total){
  __shared__ __align__(16) short Kls[2][32*64];   // [kv][dh]  rows 128B
  __shared__ __align__(16) short Vls[2][64*32];   // [dh][kv]  rows 64B
  __shared__ __align__(16) short Pls[4][16*32];   // per-wave P^T [q][kv]
  int tid = threadIdx.x;
  int lane = tid & 63, w = tid >> 6;
  int l15 = lane & 15, l4 = lane >> 4;
  int njobs = meta[58];

  for (int j = njobs - 1 - blockIdx.x; j >= 0; j -= gridDim.x){
    int word = meta[64+j];
    int b = word & 15, h = (word >> 4) & 7, c = (word >> 7) & 15, qt = word >> 11;
    int Lx = meta[b], Lm = meta[8+b];
    int ox = meta[16+b], om = meta[25+b];
    int kvc = meta[34+b], clen = meta[42+b];
    int c0 = c * clen;
    int cend = c0 + clen; if (cend > Lm) cend = Lm;
    int nt = (cend - c0 + 31) / 32;
    int qbase = qt*64 + w*16;

    __syncthreads();   // previous job's LDS reads complete

    #define ATTN_STAGE(T, BUF)                                                  \
      {                                                                         \
        int kv0_ = c0 + (T)*32;                                                 \
        int kr = tid >> 3, ks_ = tid & 7;                                       \
        int cgk = ks_ ^ (kr & 7);                                               \
        int ktok = kv0_ + kr; if (ktok >= Lm) ktok = Lm - 1;                    \
        gload16(Kb + (long)(om + ktok)*512 + h*64 + cgk*8, &Kls[BUF][tid*8]);   \
        int vr = tid >> 2, vs = tid & 3;                                        \
        int cgv = vs ^ (vr & 3);                                                \
        int vkv = kv0_ + cgv*8; if (vkv + 8 > Lm) vkv = Lm - 8;                 \
        gload16(Vt + (long)(h*64 + vr)*total + om + vkv, &Vls[BUF][tid*8]);     \
      }

    ATTN_STAGE(0, 0)

    int qr = qbase + l15;
    const short* qp = Q + (long)(ox + (qr < Lx ? qr : Lx - 1))*512 + h*64 + l4*8;
    bf8v aq0 = *(const bf8v*)qp;
    bf8v aq1 = *(const bf8v*)(qp + 32);

    float mrun = -1e30f, lrun = 0.f;
    f4v o[4];
    #pragma unroll
    for (int n = 0; n < 4; ++n) o[n] = (f4v){0.f,0.f,0.f,0.f};

    for (int t = 0; t < nt; ++t){
      __syncthreads();
      if (t + 1 < nt) ATTN_STAGE(t+1, (t+1)&1)
      int buf = t & 1;
      int kv0 = c0 + t*32;

      f4v s[2];
      #pragma unroll
      for (int n = 0; n < 2; ++n){
        int krow = n*16 + l15;
        bf8v k0 = *(const bf8v*)&Kls[buf][krow*64 + ((l4    ) ^ (krow & 7))*8];
        bf8v k1 = *(const bf8v*)&Kls[buf][krow*64 + ((4 + l4) ^ (krow & 7))*8];
        f4v z = (f4v){0.f,0.f,0.f,0.f};
        z = __builtin_amdgcn_mfma_f32_16x16x32_bf16(k0, aq0, z, 0, 0, 0);
        z = __builtin_amdgcn_mfma_f32_16x16x32_bf16(k1, aq1, z, 0, 0, 0);
        s[n] = z;
      }
      if (kv0 + 32 > cend){
        #pragma unroll
        for (int n = 0; n < 2; ++n){
          int kvb = kv0 + n*16 + 4*l4;
          #pragma unroll
          for (int jj = 0; jj < 4; ++jj)
            if (kvb + jj >= cend) s[n][jj] = -1e30f;
        }
      }
      float m1 = fmaxf(fmaxf(fmaxf(s[0][0], s[0][1]), fmaxf(s[0][2], s[0][3])),
                       fmaxf(fmaxf(s[1][0], s[1][1]), fmaxf(s[1][2], s[1][3])));
      m1 = fmaxf(m1, __shfl_xor(m1, 16, 64));
      m1 = fmaxf(m1, __shfl_xor(m1, 32, 64));
      float mnew = fmaxf(mrun, m1);
      float sc = __expf(mrun - mnew);
      mrun = mnew;
      float rs = 0.f;
      #pragma unroll
      for (int n = 0; n < 2; ++n)
        #pragma unroll
        for (int jj = 0; jj < 4; ++jj){
          float p = __expf(s[n][jj] - mnew);
          s[n][jj] = p; rs += p;
        }
      rs += __shfl_xor(rs, 16, 64);
      rs += __shfl_xor(rs, 32, 64);
      lrun = lrun * sc + rs;
      #pragma unroll
      for (int n = 0; n < 4; ++n) o[n] *= sc;

      #pragma unroll
      for (int n = 0; n < 2; ++n){
        unsigned r0, r1;
        asm("v_cvt_pk_bf16_f32 %0, %1, %2" : "=v"(r0) : "v"(s[n][0]), "v"(s[n][1]));
        asm("v_cvt_pk_bf16_f32 %0, %1, %2" : "=v"(r1) : "v"(s[n][2]), "v"(s[n][3]));
        i2v pr; pr[0] = (int)r0; pr[1] = (int)r1;
        int cs = (n*4 + l4) ^ ((l15 & 3) << 1);
        *(i2v*)&Pls[w][l15*32 + cs*4] = pr;
      }
      bf8v pb = *(const bf8v*)&Pls[w][l15*32 + (((2*l4) ^ ((l15 & 3) << 1))*4)];

      #pragma unroll
      for (int n2 = 0; n2 < 4; ++n2){
        int vrow = n2*16 + l15;
        bf8v vv = *(const bf8v*)&Vls[buf][vrow*32 + ((l4 ^ (vrow & 3))*8)];
        o[n2] = __builtin_amdgcn_mfma_f32_16x16x32_bf16(vv, pb, o[n2], 0, 0, 0);
      }
    }
    #undef ATTN_STAGE

    if (qr < Lx){
      if (kvc == 1){
        float inv = 1.f / lrun;
        long obase = (long)(ox + qr)*512 + h*64;
        #pragma unroll
        for (int n2 = 0; n2 < 4; ++n2){
          s4v ov;
          #pragma unroll
          for (int jj = 0; jj < 4; ++jj) ov[jj] = f2bf(o[n2][jj] * inv);
          *(s4v*)&Ob[obase + n2*16 + l4*4] = ov;
        }
      } else {
        long slot = ((long)(ox + qr)*8 + h)*8 + c;
        #pragma unroll
        for (int n2 = 0; n2 < 4; ++n2){
          s4v ov;
          #pragma unroll
          for (int jj = 0; jj < 4; ++jj) ov[jj] = f2bf(o[n2][jj]);
          *(s4v*)&Opart[slot*64 + n2*16 + l4*4] = ov;
        }
        if (l4 == 0){
          float2 ml; ml.x = mrun; ml.y = lrun;
          *(float2*)&mlpart[slot*2] = ml;
        }
      }
    }
  }
}

// ---------------- combine partials for split batches -------------------------
__global__ __launch_bounds__(256) void attn_combine(
    const short* __restrict__ Opart, const float* __restrict__ mlpart,
    short* __restrict__ Ob, const int* __restrict__ meta, int total){
  int w = threadIdx.x >> 6, lane = threadIdx.x & 63;
  int row = blockIdx.x*4 + w;
  if (row >= total) return;
  int b = 0;
  #pragma unroll
  for (int i = 1; i < 8; ++i) if (row >= meta[16+i]) b = i;
  int kvc = meta[34+b];
  if (kvc <= 1) return;
  for (int h = 0; h < 8; ++h){
    long sbase = ((long)row*8 + h)*8;
    float m_ = -1e30f;
    for (int c = 0; c < kvc; ++c) m_ = fmaxf(m_, mlpart[(sbase+c)*2]);
    float num = 0.f, den = 0.f;
    for (int c = 0; c < kvc; ++c){
      float mc = mlpart[(sbase+c)*2];
      float lc = mlpart[(sbase+c)*2 + 1];
      float wgt = __expf(mc - m_);
      num += wgt * bf2f(Opart[(sbase+c)*64 + lane]);
      den += wgt * lc;
    }
    Ob[(long)row*512 + h*64 + lane] = f2bf(num / den);
  }
}

// ---------------- fused residual + bf16-partial-sum + LayerNorm --------------
__global__ __launch_bounds__(256) void ln_fuse(
    const float* __restrict__ Af, const short* __restrict__ Ab,
    const short* __restrict__ PartB, int nparts, long pstride,
    const float* __restrict__ bias,
    const float* __restrict__ gamma, const float* __restrict__ beta,
    short* __restrict__ outb, float* __restrict__ outf, int rows){
  int w = threadIdx.x >> 6, lane = threadIdx.x & 63;
  long row = (long)blockIdx.x * 4 + w;
  if (row >= rows) return;
  int c0 = lane * 8;
  long base = row * 512 + c0;
  float v[8];
  if (Af){
    float4 f0 = *(const float4*)(Af + base);
    float4 f1 = *(const float4*)(Af + base + 4);
    v[0]=f0.x; v[1]=f0.y; v[2]=f0.z; v[3]=f0.w;
    v[4]=f1.x; v[5]=f1.y; v[6]=f1.z; v[7]=f1.w;
  } else {
    s8v a = *(const s8v*)(Ab + base);
    #pragma unroll
    for (int j = 0; j < 8; ++j) v[j] = bf2f(a[j]);
  }
  for (int c = 0; c < nparts; ++c){
    s8v pv = *(const s8v*)(PartB + c*pstride + base);
    #pragma unroll
    for (int j = 0; j < 8; ++j) v[j] += bf2f(pv[j]);
  }
  if (bias){
    #pragma unroll
    for (int j = 0; j < 8; ++j) v[j] += bias[c0 + j];
  }
  float sum = 0.f;
  #pragma unroll
  for (int j = 0; j < 8; ++j) sum += v[j];
  #pragma unroll
  for (int m = 1; m < 64; m <<= 1) sum += __shfl_xor(sum, m, 64);
  float mu = sum * (1.f/512.f);
  float q = 0.f;
  #pragma unroll
  for (int j = 0; j < 8; ++j){ float d = v[j] - mu; q += d*d; }
  #pragma unroll
  for (int m = 1; m < 64; m <<= 1) q += __shfl_xor(q, m, 64);
  float rs = rsqrtf(q * (1.f/512.f) + 1e-6f);
  float ov[8];
  #pragma unroll
  for (int j = 0; j < 8; ++j)
    ov[j] = (v[j] - mu) * rs * gamma[c0 + j] + beta[c0 + j];
  if (outb){
    s8v os;
    #pragma unroll
    for (int j = 0; j < 8; ++j) os[j] = f2bf(ov[j]);
    *(s8v*)(outb + base) = os;
  }
  if (outf){
    float4 f0 = {ov[0], ov[1], ov[2], ov[3]};
    float4 f1 = {ov[4], ov[5], ov[6], ov[7]};
    *(float4*)(outf + base) = f0;
    *(float4*)(outf + base + 4) = f1;
  }
}

// ---------------- host ------------------------------------------------------
extern "C" void kernel_launch(void* const* d_in, const int* in_sizes, int n_in,
                              void* d_out, int out_size, void* d_ws, size_t ws_size,
                              hipStream_t stream){
  (void)n_in; (void)out_size; (void)ws_size;
  const float* x   = (const float*)d_in[0];
  const float* mem = (const float*)d_in[1];
  const int*   lxr = (const int*)d_in[2];
  const int*   lmr = (const int*)d_in[3];
  const float* Wq  = (const float*)d_in[4];
  const float* Wk  = (const float*)d_in[5];
  const float* Wv  = (const float*)d_in[6];
  const float* Wo  = (const float*)d_in[7];
  const float* g1  = (const float*)d_in[8];
  const float* be1 = (const float*)d_in[9];
  const float* W1  = (const float*)d_in[10];
  const float* b1  = (const float*)d_in[11];
  const float* W2  = (const float*)d_in[12];
  const float* b2  = (const float*)d_in[13];
  const float* g2  = (const float*)d_in[14];
  const float* be2 = (const float*)d_in[15];
  float* out = (float*)d_out;

  int total = in_sizes[0] / 512;
  if (total <= 0) return;
  long long n = (long long)total * 512;

  char* p = (char*)d_ws;
  int*   meta  = (int*)p;    p += 16384;
  short* xb    = (short*)p;  p += n*2;
  short* mb    = (short*)p;  p += n*2;
  short* Qb    = (short*)p;  p += n*2;
  short* Kbf   = (short*)p;  p += n*2;
  short* Vtb   = (short*)p;  p += n*2;
  short* attnb = (short*)p;  p += n*2;
  short* hb    = (short*)p;  p += n*2;
  short* ffn1  = (short*)p;  p += (long long)total*2048*2;
  short* Opart = (short*)p;  p += (long long)total*8*8*64*2;
  float* mlprt = (float*)p;  p += (long long)total*8*8*2*4;
  short* p_wo  = (short*)p;  p += n*2*2;   // 2 bf16 partial chunks
  short* p_ff  = (short*)p;  p += n*4*2;   // 4 bf16 partial chunks
  short* WqT   = (short*)p;  p += 512*512*2;
  short* WkT   = (short*)p;  p += 512*512*2;
  short* WvT   = (short*)p;  p += 512*512*2;
  short* WoT   = (short*)p;  p += 512*512*2;
  short* W1T   = (short*)p;  p += 2048*512*2;
  short* W2T   = (short*)p;  p += 512*2048*2;

  int nblk_cvt = (int)(((2*n)/8 + 255) / 256);
  setup_kernel<<<dim3((unsigned)(1 + nblk_cvt + 3072)), 256, 0, stream>>>(
      lxr, lmr, meta, x, mem, xb, mb, n, nblk_cvt,
      Wq, Wk, Wv, Wo, W1, W2, WqT, WkT, WvT, WoT, W1T, W2T);

  int mt64 = (total + 63)/64;
  gemm_qkv<<<dim3(12, mt64), 256, 0, stream>>>(xb, mb, WqT, WkT, WvT, Qb, Kbf, Vtb, total);

  attn_kernel<<<dim3(2048), 256, 0, stream>>>(Qb, Kbf, Vtb, attnb,
                                              Opart, mlprt, meta, total);
  attn_combine<<<dim3((unsigned)((total + 3)/4)), 256, 0, stream>>>(
      Opart, mlprt, attnb, meta, total);

  // Wo: K=512 split into 2 chunks of 256 -> bf16 partials
  gemm64<<<dim3(4, mt64, 2), 256, 0, stream>>>(attnb, WoT, p_wo, nullptr,
                                               total, 512, 512, 256, 1.f, 0, 0);
  // ln1: h = LN(x + p_wo[0] + p_wo[1]) -> bf16
  ln_fuse<<<dim3((unsigned)((total + 3)/4)), 256, 0, stream>>>(
      x, nullptr, p_wo, 2, n, nullptr, g1, be1, hb, nullptr, total);

  // FFN1: bf16 out with bias+relu
  gemm64<<<dim3(16, mt64, 1), 256, 0, stream>>>(hb, W1T, ffn1, b1,
                                                total, 2048, 512, 512, 1.f, 1, 0);
  // FFN2: K=2048 split into 4 chunks of 512 -> bf16 partials
  gemm64<<<dim3(4, mt64, 4), 256, 0, stream>>>(ffn1, W2T, p_ff, nullptr,
                                               total, 512, 2048, 512, 1.f, 0, 0);
  // ln2: out = LN(h + sum p_ff + b2) -> f32
  ln_fuse<<<dim3((unsigned)((total + 3)/4)), 256, 0, stream>>>(
      nullptr, hb, p_ff, 4, n, b2, g2, be2, nullptr, out, total);
}

// Round 15
// 164.347 us; speedup vs baseline: 1.1092x; 1.1092x over previous
//
#include <hip/hip_runtime.h>
#include <stdint.h>

typedef short bf8v __attribute__((ext_vector_type(8)));
typedef float f4v  __attribute__((ext_vector_type(4)));
typedef short s8v  __attribute__((ext_vector_type(8)));
typedef short s4v  __attribute__((ext_vector_type(4)));
typedef int   i2v  __attribute__((ext_vector_type(2)));

__device__ __forceinline__ float bf2f(short b){
  unsigned u = ((unsigned)(unsigned short)b) << 16;
  union { unsigned u; float f; } c; c.u = u; return c.f;
}
__device__ __forceinline__ short f2bf(float f){
  union { float f; unsigned u; } c; c.f = f;
  unsigned r = (c.u + 0x7FFFu + ((c.u >> 16) & 1u)) >> 16;
  return (short)r;
}
__device__ __forceinline__ void gload16(const short* g, short* l){
  __builtin_amdgcn_global_load_lds(
      (const __attribute__((address_space(1))) void*)g,
      (__attribute__((address_space(3))) void*)l, 16, 0, 0);
}
// bijective XCD regroup (m204): logical work index such that each XCD gets a
// contiguous chunk of the logical range; consecutive logical ids share an XCD.
__device__ __forceinline__ int xcd_remap(int wg, int nwg){
  int q = nwg >> 3, r = nwg & 7;
  int xcd = wg & 7, idx = wg >> 3;
  return (xcd < r ? xcd*(q+1) : r*(q+1) + (xcd - r)*q) + idx;
}

// ---------------- setup: prep (block 0) + cvt2bf + weight transpose ----------
__global__ __launch_bounds__(256) void setup_kernel(
    const int* lx, const int* lm, int* meta,
    const float* __restrict__ x, const float* __restrict__ mem,
    short* __restrict__ xb, short* __restrict__ mb, long long n, int nblk_cvt,
    const float* __restrict__ Wq, const float* __restrict__ Wk,
    const float* __restrict__ Wv, const float* __restrict__ Wo,
    const float* __restrict__ W1, const float* __restrict__ W2,
    short* __restrict__ WqT, short* __restrict__ WkT,
    short* __restrict__ WvT, short* __restrict__ WoT,
    short* __restrict__ W1T, short* __restrict__ W2T){
  __shared__ int sjp[9], skvc[8];
  __shared__ float tile[32][33];
  int tid = threadIdx.x;
  int bid = blockIdx.x;

  if (bid == 0){
    if (tid == 0){
      int is64 = ((lx[1] | lx[3] | lx[5] | lx[7]) == 0) ? 1 : 0;
      int ox = 0, om = 0;
      for (int b = 0; b < 8; ++b){
        int a = is64 ? lx[2*b] : lx[b];
        int c = is64 ? lm[2*b] : lm[b];
        meta[b] = a; meta[8+b] = c;
        meta[16+b] = ox; meta[25+b] = om;
        ox += a; om += c;
      }
      meta[24] = ox; meta[33] = om;
      int jp = 0;
      for (int b = 0; b < 8; ++b){
        int Lm_ = meta[8+b];
        int kvc = (Lm_ + 255) / 256; if (kvc > 4) kvc = 4; if (kvc < 1) kvc = 1;
        int clen = (((Lm_ + kvc - 1) / kvc) + 31) & ~31;
        meta[34+b] = kvc; meta[42+b] = clen;
        meta[50+b] = jp;
        sjp[b] = jp; skvc[b] = kvc;
        int qt = (meta[b] + 63) / 64;
        jp += qt * kvc * 8;
      }
      meta[58] = jp;
      sjp[8] = jp;
    }
    __syncthreads();
    int njobs = sjp[8];
    for (int j = tid; j < njobs; j += blockDim.x){
      int b = 0;
      #pragma unroll
      for (int i = 1; i < 8; ++i) if (j >= sjp[i]) b = i;
      int local = j - sjp[b];
      int kvc = skvc[b];
      int h = local & 7;
      int r = local >> 3;
      int c = r % kvc;
      int qt = r / kvc;
      meta[64+j] = b | (h << 4) | (c << 7) | (qt << 11);
    }
    return;
  }

  if (bid <= nblk_cvt){
    long long t = (long long)(bid - 1) * 256 + tid;
    long long i = t * 8;
    const float* s; short* d;
    if (i < n){ s = x + i; d = xb + i; }
    else {
      i -= n; if (i >= n) return;
      s = mem + i; d = mb + i;
    }
    float4 f0 = *(const float4*)s;
    float4 f1 = *(const float4*)(s + 4);
    s8v o;
    o[0]=f2bf(f0.x); o[1]=f2bf(f0.y); o[2]=f2bf(f0.z); o[3]=f2bf(f0.w);
    o[4]=f2bf(f1.x); o[5]=f2bf(f1.y); o[6]=f2bf(f1.z); o[7]=f2bf(f1.w);
    *(s8v*)d = o;
    return;
  }

  int wbid = bid - 1 - nblk_cvt;       // 0 .. 3071
  const float* W; short* WT; int K, N, t0;
  if      (wbid <  256){ W=Wq; WT=WqT; K=512;  N=512;  t0=0;    }
  else if (wbid <  512){ W=Wk; WT=WkT; K=512;  N=512;  t0=256;  }
  else if (wbid <  768){ W=Wv; WT=WvT; K=512;  N=512;  t0=512;  }
  else if (wbid < 1024){ W=Wo; WT=WoT; K=512;  N=512;  t0=768;  }
  else if (wbid < 2048){ W=W1; WT=W1T; K=512;  N=2048; t0=1024; }
  else                 { W=W2; WT=W2T; K=2048; N=512;  t0=2048; }
  int lt = wbid - t0;
  int ntn = N / 32;
  int tk = lt / ntn, tn = lt % ntn;
  int r0 = tid >> 5, c = tid & 31;
  #pragma unroll
  for (int i = 0; i < 4; ++i){
    int r = r0 + i*8;
    tile[r][c] = W[(long)(tk*32 + r)*N + tn*32 + c];
  }
  __syncthreads();
  #pragma unroll
  for (int i = 0; i < 4; ++i){
    int r = r0 + i*8;
    WT[(long)(tn*32 + r)*K + tk*32 + c] = f2bf(tile[c][r]);
  }
}

// ---------------- bf16 MFMA GEMM core (BM=64 x BN=128, BK=32), K-chunked -----
__device__ __forceinline__ void stage_g64(const short* A, const short* Bt,
    long brow, long bcol, int M, int N, int K, int t,
    short* Als, short* Bls){
  int tid = threadIdx.x;
  {
    int cc = tid;
    int row = cc >> 2, slot = cc & 3;
    int cg = slot ^ ((row >> 1) & 3);
    long ar = brow + row; if (ar >= M) ar = M - 1;
    gload16(A + ar*(long)K + t + cg*8, &Als[cc*8]);
  }
  #pragma unroll
  for (int i = 0; i < 2; ++i){
    int cc = i*256 + tid;
    int row = cc >> 2, slot = cc & 3;
    int cg = slot ^ ((row >> 1) & 3);
    long br = bcol + row; if (br >= N) br = N - 1;
    gload16(Bt + br*(long)K + t + cg*8, &Bls[cc*8]);
  }
}

__device__ __forceinline__ void gemm_core64(const short* A, const short* Bt,
    short* __restrict__ Cb, const float* __restrict__ bias,
    int M, int N, int K, int k0, int klen,
    float scale, int relu, int colmajor,
    long brow, long bcol, short* Als, short* Bls){
  int tid = threadIdx.x;
  int lane = tid & 63, w = tid >> 6;
  int wcol = w * 32;
  int l15 = lane & 15, l4 = lane >> 4;

  f4v acc[4][2];
  #pragma unroll
  for (int m = 0; m < 4; ++m)
    #pragma unroll
    for (int n = 0; n < 2; ++n) acc[m][n] = (f4v){0.f,0.f,0.f,0.f};

  int nt = klen / 32;
  stage_g64(A, Bt, brow, bcol, M, N, K, k0, Als, Bls);
  for (int t = 0; t < nt; ++t){
    __syncthreads();            // stage(t) landed; buf[(t+1)&1] free
    if (t + 1 < nt)
      stage_g64(A, Bt, brow, bcol, M, N, K, k0 + (t+1)*32,
                Als + ((t+1)&1)*2048, Bls + ((t+1)&1)*4096);
    const short* Ab = Als + (t&1)*2048;
    const short* Bb = Bls + (t&1)*4096;
    bf8v a[4], b[2];
    #pragma unroll
    for (int m = 0; m < 4; ++m){
      int row = m*16 + l15;
      a[m] = *(const bf8v*)&Ab[row*32 + (l4 ^ ((row >> 1) & 3))*8];
    }
    #pragma unroll
    for (int n = 0; n < 2; ++n){
      int row = wcol + n*16 + l15;
      b[n] = *(const bf8v*)&Bb[row*32 + (l4 ^ ((row >> 1) & 3))*8];
    }
    #pragma unroll
    for (int m = 0; m < 4; ++m){
      acc[m][0] = __builtin_amdgcn_mfma_f32_16x16x32_bf16(a[m], b[0], acc[m][0], 0, 0, 0);
      acc[m][1] = __builtin_amdgcn_mfma_f32_16x16x32_bf16(a[m], b[1], acc[m][1], 0, 0, 0);
    }
  }

  #pragma unroll
  for (int m = 0; m < 4; ++m){
    #pragma unroll
    for (int n = 0; n < 2; ++n){
      long col = bcol + wcol + n*16 + l15;
      float bi = (bias != nullptr && col < N) ? bias[col] : 0.f;
      #pragma unroll
      for (int j = 0; j < 4; ++j){
        long row = brow + m*16 + 4*l4 + j;
        if (row < M && col < N){
          float v = acc[m][n][j] * scale + bi;
          if (relu) v = fmaxf(v, 0.f);
          Cb[colmajor ? (col*(long)M + row) : (row*(long)N + col)] = f2bf(v);
        }
      }
    }
  }
}

// generic launcher: grid = (ncol, nrow, nchunk), XCD-swizzled; chunk c -> C+c*M*N
__global__ __launch_bounds__(256) void gemm64(
    const short* __restrict__ A, const short* __restrict__ Bt,
    short* __restrict__ C, const float* __restrict__ bias,
    int M, int N, int K, int klen, float scale, int relu, int colmajor){
  __shared__ __align__(16) short Als[2*64*32];
  __shared__ __align__(16) short Bls[2*128*32];
  int ncol = gridDim.x, nrow = gridDim.y;
  int nwg = ncol * nrow * gridDim.z;
  int wg = blockIdx.x + ncol*(blockIdx.y + nrow*blockIdx.z);
  int lg = xcd_remap(wg, nwg);
  int xx = lg % ncol;
  int yy = (lg / ncol) % nrow;
  int chunk = lg / (ncol * nrow);
  gemm_core64(A, Bt, C + (long)chunk * M * N, bias, M, N, K, chunk*klen, klen,
              scale, relu, colmajor,
              (long)yy * 64, (long)xx * 128, Als, Bls);
}

// fused QKV (XCD-swizzled): 12 x-tiles (4 col-tiles x {Q,K,V}).
__global__ __launch_bounds__(256) void gemm_qkv(
    const short* __restrict__ xb, const short* __restrict__ mb,
    const short* __restrict__ WqT, const short* __restrict__ WkT,
    const short* __restrict__ WvT,
    short* __restrict__ Qb, short* __restrict__ Kbf, short* __restrict__ Vtb,
    int total){
  __shared__ __align__(16) short Als[2*64*32];
  __shared__ __align__(16) short Bls[2*128*32];
  int nwg = 12 * gridDim.y;
  int wg = blockIdx.x + 12*blockIdx.y;
  int lg = xcd_remap(wg, nwg);
  int xx = lg % 12;
  int yy = lg / 12;
  int seg = xx >> 2;
  const short* A  = (seg == 0) ? xb : mb;
  const short* Bt = (seg == 0) ? WqT : ((seg == 1) ? WkT : WvT);
  short* C        = (seg == 0) ? Qb  : ((seg == 1) ? Kbf : Vtb);
  float scale     = (seg == 0) ? 0.125f : 1.f;
  int colmajor    = (seg == 2);
  gemm_core64(A, Bt, C, nullptr, total, 512, 512, 0, 512, scale, 0, colmajor,
              (long)yy * 64, (long)(xx & 3) * 128, Als, Bls);
}

// ---------------- flash attention: split-kv jobs, swapped QK^T ---------------
__global__ __launch_bounds__(256) void attn_kernel(
    const short* __restrict__ Q, const short* __restrict__ Kb,
    const short* __restrict__ Vt, short* __restrict__ Ob,
    short* __restrict__ Opart, float* __restrict__ mlpart,
    const int* __restrict__ meta, int total){
  __shared__ __align__(16) short Kls[2][32*64];   // [kv][dh]  rows 128B
  __shared__ __align__(16) short Vls[2][64*32];   // [dh][kv]  rows 64B
  __shared__ __align__(16) short Pls[4][16*32];   // per-wave P^T [q][kv]
  int tid = threadIdx.x;
  int lane = tid & 63, w = tid >> 6;
  int l15 = lane & 15, l4 = lane >> 4;
  int njobs = meta[58];

  // longest jobs are at the end of the list -> iterate in reverse so the
  // 8-iter chunks start first (better tail behavior)
  for (int j = njobs - 1 - blockIdx.x; j >= 0; j -= gridDim.x){
    int word = meta[64+j];
    int b = word & 15, h = (word >> 4) & 7, c = (word >> 7) & 15, qt = word >> 11;
    int Lx = meta[b], Lm = meta[8+b];
    int ox = meta[16+b], om = meta[25+b];
    int kvc = meta[34+b], clen = meta[42+b];
    int c0 = c * clen;
    int cend = c0 + clen; if (cend > Lm) cend = Lm;
    int nt = (cend - c0 + 31) / 32;
    int qbase = qt*64 + w*16;

    __syncthreads();   // previous job's LDS reads complete

    #define ATTN_STAGE(T, BUF)                                                  \
      {                                                                         \
        int kv0_ = c0 + (T)*32;                                                 \
        int kr = tid >> 3, ks_ = tid & 7;                                       \
        int cgk = ks_ ^ (kr & 7);                                               \
        int ktok = kv0_ + kr; if (ktok >= Lm) ktok = Lm - 1;                    \
        gload16(Kb + (long)(om + ktok)*512 + h*64 + cgk*8, &Kls[BUF][tid*8]);   \
        int vr = tid >> 2, vs = tid & 3;                                        \
        int cgv = vs ^ (vr & 3);                                                \
        int vkv = kv0_ + cgv*8; if (vkv + 8 > Lm) vkv = Lm - 8;                 \
        gload16(Vt + (long)(h*64 + vr)*total + om + vkv, &Vls[BUF][tid*8]);     \
      }

    ATTN_STAGE(0, 0)

    int qr = qbase + l15;
    const short* qp = Q + (long)(ox + (qr < Lx ? qr : Lx - 1))*512 + h*64 + l4*8;
    bf8v aq0 = *(const bf8v*)qp;
    bf8v aq1 = *(const bf8v*)(qp + 32);

    float mrun = -1e30f, lrun = 0.f;
    f4v o[4];
    #pragma unroll
    for (int n = 0; n < 4; ++n) o[n] = (f4v){0.f,0.f,0.f,0.f};

    for (int t = 0; t < nt; ++t){
      __syncthreads();
      if (t + 1 < nt) ATTN_STAGE(t+1, (t+1)&1)
      int buf = t & 1;
      int kv0 = c0 + t*32;

      f4v s[2];
      #pragma unroll
      for (int n = 0; n < 2; ++n){
        int krow = n*16 + l15;
        bf8v k0 = *(const bf8v*)&Kls[buf][krow*64 + ((l4    ) ^ (krow & 7))*8];
        bf8v k1 = *(const bf8v*)&Kls[buf][krow*64 + ((4 + l4) ^ (krow & 7))*8];
        f4v z = (f4v){0.f,0.f,0.f,0.f};
        z = __builtin_amdgcn_mfma_f32_16x16x32_bf16(k0, aq0, z, 0, 0, 0);
        z = __builtin_amdgcn_mfma_f32_16x16x32_bf16(k1, aq1, z, 0, 0, 0);
        s[n] = z;
      }
      if (kv0 + 32 > cend){
        #pragma unroll
        for (int n = 0; n < 2; ++n){
          int kvb = kv0 + n*16 + 4*l4;
          #pragma unroll
          for (int jj = 0; jj < 4; ++jj)
            if (kvb + jj >= cend) s[n][jj] = -1e30f;
        }
      }
      float m1 = fmaxf(fmaxf(fmaxf(s[0][0], s[0][1]), fmaxf(s[0][2], s[0][3])),
                       fmaxf(fmaxf(s[1][0], s[1][1]), fmaxf(s[1][2], s[1][3])));
      m1 = fmaxf(m1, __shfl_xor(m1, 16, 64));
      m1 = fmaxf(m1, __shfl_xor(m1, 32, 64));
      float mnew = fmaxf(mrun, m1);
      float sc = __expf(mrun - mnew);
      mrun = mnew;
      float rs = 0.f;
      #pragma unroll
      for (int n = 0; n < 2; ++n)
        #pragma unroll
        for (int jj = 0; jj < 4; ++jj){
          float p = __expf(s[n][jj] - mnew);
          s[n][jj] = p; rs += p;
        }
      rs += __shfl_xor(rs, 16, 64);
      rs += __shfl_xor(rs, 32, 64);
      lrun = lrun * sc + rs;
      #pragma unroll
      for (int n = 0; n < 4; ++n) o[n] *= sc;

      #pragma unroll
      for (int n = 0; n < 2; ++n){
        unsigned r0, r1;
        asm("v_cvt_pk_bf16_f32 %0, %1, %2" : "=v"(r0) : "v"(s[n][0]), "v"(s[n][1]));
        asm("v_cvt_pk_bf16_f32 %0, %1, %2" : "=v"(r1) : "v"(s[n][2]), "v"(s[n][3]));
        i2v pr; pr[0] = (int)r0; pr[1] = (int)r1;
        int cs = (n*4 + l4) ^ ((l15 & 3) << 1);
        *(i2v*)&Pls[w][l15*32 + cs*4] = pr;
      }
      bf8v pb = *(const bf8v*)&Pls[w][l15*32 + (((2*l4) ^ ((l15 & 3) << 1))*4)];

      #pragma unroll
      for (int n2 = 0; n2 < 4; ++n2){
        int vrow = n2*16 + l15;
        bf8v vv = *(const bf8v*)&Vls[buf][vrow*32 + ((l4 ^ (vrow & 3))*8)];
        o[n2] = __builtin_amdgcn_mfma_f32_16x16x32_bf16(vv, pb, o[n2], 0, 0, 0);
      }
    }
    #undef ATTN_STAGE

    if (qr < Lx){
      if (kvc == 1){
        float inv = 1.f / lrun;
        long obase = (long)(ox + qr)*512 + h*64;
        #pragma unroll
        for (int n2 = 0; n2 < 4; ++n2){
          s4v ov;
          #pragma unroll
          for (int jj = 0; jj < 4; ++jj) ov[jj] = f2bf(o[n2][jj] * inv);
          *(s4v*)&Ob[obase + n2*16 + l4*4] = ov;
        }
      } else {
        long slot = ((long)(ox + qr)*8 + h)*4 + c;
        #pragma unroll
        for (int n2 = 0; n2 < 4; ++n2){
          s4v ov;
          #pragma unroll
          for (int jj = 0; jj < 4; ++jj) ov[jj] = f2bf(o[n2][jj]);
          *(s4v*)&Opart[slot*64 + n2*16 + l4*4] = ov;
        }
        if (l4 == 0){
          float2 ml; ml.x = mrun; ml.y = lrun;
          *(float2*)&mlpart[slot*2] = ml;
        }
      }
    }
  }
}

// ---------------- combine partials for split batches -------------------------
__global__ __launch_bounds__(256) void attn_combine(
    const short* __restrict__ Opart, const float* __restrict__ mlpart,
    short* __restrict__ Ob, const int* __restrict__ meta, int total){
  int w = threadIdx.x >> 6, lane = threadIdx.x & 63;
  int row = blockIdx.x*4 + w;
  if (row >= total) return;
  int b = 0;
  #pragma unroll
  for (int i = 1; i < 8; ++i) if (row >= meta[16+i]) b = i;
  int kvc = meta[34+b];
  if (kvc <= 1) return;
  for (int h = 0; h < 8; ++h){
    long sbase = ((long)row*8 + h)*4;
    float m_ = -1e30f;
    for (int c = 0; c < kvc; ++c) m_ = fmaxf(m_, mlpart[(sbase+c)*2]);
    float num = 0.f, den = 0.f;
    for (int c = 0; c < kvc; ++c){
      float mc = mlpart[(sbase+c)*2];
      float lc = mlpart[(sbase+c)*2 + 1];
      float wgt = __expf(mc - m_);
      num += wgt * bf2f(Opart[(sbase+c)*64 + lane]);
      den += wgt * lc;
    }
    Ob[(long)row*512 + h*64 + lane] = f2bf(num / den);
  }
}

// ---------------- fused residual + bf16-partial-sum + LayerNorm --------------
__global__ __launch_bounds__(256) void ln_fuse(
    const float* __restrict__ Af, const short* __restrict__ Ab,
    const short* __restrict__ PartB, int nparts, long pstride,
    const float* __restrict__ bias,
    const float* __restrict__ gamma, const float* __restrict__ beta,
    short* __restrict__ outb, float* __restrict__ outf, int rows){
  int w = threadIdx.x >> 6, lane = threadIdx.x & 63;
  long row = (long)blockIdx.x * 4 + w;
  if (row >= rows) return;
  int c0 = lane * 8;
  long base = row * 512 + c0;
  float v[8];
  if (Af){
    float4 f0 = *(const float4*)(Af + base);
    float4 f1 = *(const float4*)(Af + base + 4);
    v[0]=f0.x; v[1]=f0.y; v[2]=f0.z; v[3]=f0.w;
    v[4]=f1.x; v[5]=f1.y; v[6]=f1.z; v[7]=f1.w;
  } else {
    s8v a = *(const s8v*)(Ab + base);
    #pragma unroll
    for (int j = 0; j < 8; ++j) v[j] = bf2f(a[j]);
  }
  for (int c = 0; c < nparts; ++c){
    s8v pv = *(const s8v*)(PartB + c*pstride + base);
    #pragma unroll
    for (int j = 0; j < 8; ++j) v[j] += bf2f(pv[j]);
  }
  if (bias){
    #pragma unroll
    for (int j = 0; j < 8; ++j) v[j] += bias[c0 + j];
  }
  float sum = 0.f;
  #pragma unroll
  for (int j = 0; j < 8; ++j) sum += v[j];
  #pragma unroll
  for (int m = 1; m < 64; m <<= 1) sum += __shfl_xor(sum, m, 64);
  float mu = sum * (1.f/512.f);
  float q = 0.f;
  #pragma unroll
  for (int j = 0; j < 8; ++j){ float d = v[j] - mu; q += d*d; }
  #pragma unroll
  for (int m = 1; m < 64; m <<= 1) q += __shfl_xor(q, m, 64);
  float rs = rsqrtf(q * (1.f/512.f) + 1e-6f);
  float ov[8];
  #pragma unroll
  for (int j = 0; j < 8; ++j)
    ov[j] = (v[j] - mu) * rs * gamma[c0 + j] + beta[c0 + j];
  if (outb){
    s8v os;
    #pragma unroll
    for (int j = 0; j < 8; ++j) os[j] = f2bf(ov[j]);
    *(s8v*)(outb + base) = os;
  }
  if (outf){
    float4 f0 = {ov[0], ov[1], ov[2], ov[3]};
    float4 f1 = {ov[4], ov[5], ov[6], ov[7]};
    *(float4*)(outf + base) = f0;
    *(float4*)(outf + base + 4) = f1;
  }
}

// ---------------- host ------------------------------------------------------
extern "C" void kernel_launch(void* const* d_in, const int* in_sizes, int n_in,
                              void* d_out, int out_size, void* d_ws, size_t ws_size,
                              hipStream_t stream){
  (void)n_in; (void)out_size; (void)ws_size;
  const float* x   = (const float*)d_in[0];
  const float* mem = (const float*)d_in[1];
  const int*   lxr = (const int*)d_in[2];
  const int*   lmr = (const int*)d_in[3];
  const float* Wq  = (const float*)d_in[4];
  const float* Wk  = (const float*)d_in[5];
  const float* Wv  = (const float*)d_in[6];
  const float* Wo  = (const float*)d_in[7];
  const float* g1  = (const float*)d_in[8];
  const float* be1 = (const float*)d_in[9];
  const float* W1  = (const float*)d_in[10];
  const float* b1  = (const float*)d_in[11];
  const float* W2  = (const float*)d_in[12];
  const float* b2  = (const float*)d_in[13];
  const float* g2  = (const float*)d_in[14];
  const float* be2 = (const float*)d_in[15];
  float* out = (float*)d_out;

  int total = in_sizes[0] / 512;
  if (total <= 0) return;
  long long n = (long long)total * 512;

  char* p = (char*)d_ws;
  int*   meta  = (int*)p;    p += 16384;
  short* xb    = (short*)p;  p += n*2;
  short* mb    = (short*)p;  p += n*2;
  short* Qb    = (short*)p;  p += n*2;
  short* Kbf   = (short*)p;  p += n*2;
  short* Vtb   = (short*)p;  p += n*2;
  short* attnb = (short*)p;  p += n*2;
  short* hb    = (short*)p;  p += n*2;
  short* ffn1  = (short*)p;  p += (long long)total*2048*2;
  short* Opart = (short*)p;  p += (long long)total*8*4*64*2;
  float* mlprt = (float*)p;  p += (long long)total*8*4*2*4;
  short* p_wo  = (short*)p;  p += n*2*2;   // 2 bf16 partial chunks
  short* p_ff  = (short*)p;  p += n*4*2;   // 4 bf16 partial chunks
  short* WqT   = (short*)p;  p += 512*512*2;
  short* WkT   = (short*)p;  p += 512*512*2;
  short* WvT   = (short*)p;  p += 512*512*2;
  short* WoT   = (short*)p;  p += 512*512*2;
  short* W1T   = (short*)p;  p += 2048*512*2;
  short* W2T   = (short*)p;  p += 512*2048*2;

  int nblk_cvt = (int)(((2*n)/8 + 255) / 256);
  setup_kernel<<<dim3((unsigned)(1 + nblk_cvt + 3072)), 256, 0, stream>>>(
      lxr, lmr, meta, x, mem, xb, mb, n, nblk_cvt,
      Wq, Wk, Wv, Wo, W1, W2, WqT, WkT, WvT, WoT, W1T, W2T);

  int mt64 = (total + 63)/64;
  gemm_qkv<<<dim3(12, mt64), 256, 0, stream>>>(xb, mb, WqT, WkT, WvT, Qb, Kbf, Vtb, total);

  attn_kernel<<<dim3(2048), 256, 0, stream>>>(Qb, Kbf, Vtb, attnb,
                                              Opart, mlprt, meta, total);
  attn_combine<<<dim3((unsigned)((total + 3)/4)), 256, 0, stream>>>(
      Opart, mlprt, attnb, meta, total);

  // Wo: K=512 split into 2 chunks of 256 -> bf16 partials
  gemm64<<<dim3(4, mt64, 2), 256, 0, stream>>>(attnb, WoT, p_wo, nullptr,
                                               total, 512, 512, 256, 1.f, 0, 0);
  // ln1: h = LN(x + p_wo[0] + p_wo[1]) -> bf16
  ln_fuse<<<dim3((unsigned)((total + 3)/4)), 256, 0, stream>>>(
      x, nullptr, p_wo, 2, n, nullptr, g1, be1, hb, nullptr, total);

  // FFN1: bf16 out with bias+relu
  gemm64<<<dim3(16, mt64, 1), 256, 0, stream>>>(hb, W1T, ffn1, b1,
                                                total, 2048, 512, 512, 1.f, 1, 0);
  // FFN2: K=2048 split into 4 chunks of 512 -> bf16 partials
  gemm64<<<dim3(4, mt64, 4), 256, 0, stream>>>(ffn1, W2T, p_ff, nullptr,
                                               total, 512, 2048, 512, 1.f, 0, 0);
  // ln2: out = LN(h + sum p_ff + b2) -> f32
  ln_fuse<<<dim3((unsigned)((total + 3)/4)), 256, 0, stream>>>(
      nullptr, hb, p_ff, 4, n, b2, g2, be2, nullptr, out, total);
}